// Round 13
// baseline (260.556 us; speedup 1.0000x reference)
//
#include <hip/hip_runtime.h>

typedef unsigned short u16;
typedef unsigned int u32;
typedef unsigned long long u64;
using s16x8 = __attribute__((ext_vector_type(8))) short;
using s16x4 = __attribute__((ext_vector_type(4))) short;
using u16x4 = __attribute__((ext_vector_type(4))) unsigned short;
using u32x4 = __attribute__((ext_vector_type(4))) unsigned int;
using f32x4 = __attribute__((ext_vector_type(4))) float;

__device__ __forceinline__ u16 f2bf(float f) {
  unsigned int u = __float_as_uint(f);
  u += 0x7FFFu + ((u >> 16) & 1u);
  return (u16)(u >> 16);
}
__device__ __forceinline__ float bf2f(u16 b) {
  return __uint_as_float(((u32)b) << 16);
}
__device__ __forceinline__ u32 pkbf(float a, float b) {
  u32 r;
  asm("v_cvt_pk_bf16_f32 %0, %1, %2" : "=v"(r) : "v"(a), "v"(b));
  return r;
}
// single v_cmp producing a 64-bit lane mask in SGPRs: key >= cand
__device__ __forceinline__ u64 cmp_ge(u32 key, u32 cand) {
  u64 m;
  asm("v_cmp_le_u32 %0, %1, %2" : "=s"(m) : "s"(cand), "v"(key));
  return m;
}
// monotone 16-bit key from f32 (sign-flip trick, truncated) — r9-proven
__device__ __forceinline__ u32 f2key(float f) {
  u32 u = __float_as_uint(f);
  u32 flip = (u32)((int)u >> 31) | 0x80000000u;
  return (u ^ flip) >> 16;
}
// inverse: 16-bit key -> f32 (truncated value)
__device__ __forceinline__ float key2f(u32 k) {
  u32 t = k << 16;
  u32 msk = ((int)t < 0) ? 0x80000000u : 0xFFFF0000u;
  return __uint_as_float(t ^ msk);
}

// ---------------- prep: weight transposes only (64x64 LDS tiles) ----------------
// B2 is written as B2T4: B2T replicated 4x along K (for the jc-split FFN partials).
__global__ __launch_bounds__(256) void prep_w(
    const float* __restrict__ Wq, const float* __restrict__ Wk, const float* __restrict__ Wv,
    const float* __restrict__ Wo, const float* __restrict__ A1, const float* __restrict__ B1,
    const float* __restrict__ A2, const float* __restrict__ B2,
    u16* __restrict__ WqT, u16* __restrict__ WkT, u16* __restrict__ WvT, u16* __restrict__ WoT,
    u16* __restrict__ A1T, u16* __restrict__ B1T, u16* __restrict__ A2T, u16* __restrict__ B2T4) {
  __shared__ u16 t[64][68];
  int b = blockIdx.x, tid = threadIdx.x;
  const float* src; u16* dst; int base, R, C;
  bool is_b2 = false;
  if (b < 64)        { src = Wq; dst = WqT; base = 0;   R = 512;  C = 512; }
  else if (b < 128)  { src = Wk; dst = WkT; base = 64;  R = 512;  C = 512; }
  else if (b < 192)  { src = Wv; dst = WvT; base = 128; R = 512;  C = 512; }
  else if (b < 256)  { src = Wo; dst = WoT; base = 192; R = 512;  C = 512; }
  else if (b < 264)  { src = A1; dst = A1T; base = 256; R = 512;  C = 64;  }
  else if (b < 296)  { src = B1; dst = B1T; base = 264; R = 64;   C = 2048;}
  else if (b < 328)  { src = A2; dst = A2T; base = 296; R = 2048; C = 64;  }
  else               { src = B2; dst = B2T4; base = 328; R = 64;  C = 512; is_b2 = true; }
  int ti = b - base;
  int tpr = C >> 6;
  int r0 = (ti / tpr) * 64, c0 = (ti % tpr) * 64;
#pragma unroll
  for (int i = 0; i < 4; ++i) {
    int r = i * 16 + (tid >> 4), c = (tid & 15) * 4;
    float4 f = *(const float4*)&src[(size_t)(r0 + r) * C + c0 + c];
    t[r][c] = f2bf(f.x); t[r][c + 1] = f2bf(f.y);
    t[r][c + 2] = f2bf(f.z); t[r][c + 3] = f2bf(f.w);
  }
  __syncthreads();
#pragma unroll
  for (int i = 0; i < 4; ++i) {
    int cc = i * 16 + (tid >> 4), rr = (tid & 15) * 4;
    u16x4 o;
    o[0] = t[rr][cc]; o[1] = t[rr + 1][cc]; o[2] = t[rr + 2][cc]; o[3] = t[rr + 3][cc];
    if (is_b2) {
#pragma unroll
      for (int rep = 0; rep < 4; ++rep)
        *(u16x4*)&dst[(size_t)(c0 + cc) * 256 + rep * 64 + r0 + rr] = o;
    } else {
      *(u16x4*)&dst[(size_t)(c0 + cc) * R + r0 + rr] = o;
    }
  }
}

// ---------------- fused QKV projection from f32 inputs: 128x128 tiles, grid (4,64,3) ----
// z=0: Q (scaled 0.125*log2e, scatter [nh][l][d]); z=1: K ([nh][l][d]); z=2: V ([nh][d][l]).
__global__ __launch_bounds__(256, 4) void qkv_fused(
    const float* __restrict__ q, const float* __restrict__ k, const float* __restrict__ v,
    const u16* __restrict__ WqT, const u16* __restrict__ WkT, const u16* __restrict__ WvT,
    const float* __restrict__ bq, const float* __restrict__ bk, const float* __restrict__ bv,
    u16* __restrict__ Qw, u16* __restrict__ Kw, u16* __restrict__ Vw) {
  __shared__ __align__(16) u16 As[128][72];
  __shared__ __align__(16) u16 Bs[128][72];
  const int z = blockIdx.z;
  const float* A = z == 0 ? q : (z == 1 ? k : v);
  const u16* Bt = z == 0 ? WqT : (z == 1 ? WkT : WvT);
  const float* bias = z == 0 ? bq : (z == 1 ? bk : bv);
  u16* outp = z == 0 ? Qw : (z == 1 ? Kw : Vw);

  const int tid = threadIdx.x;
  const int m0 = blockIdx.y * 128, n0 = blockIdx.x * 128;
  const int lane = tid & 63, wid = tid >> 6;
  const int l16 = lane & 15, hi = lane >> 4;
  const int wr = (wid >> 1) * 64, wc = (wid & 1) * 64;

  f32x4 acc[4][4];
#pragma unroll
  for (int i = 0; i < 4; ++i)
#pragma unroll
    for (int j = 0; j < 4; ++j) acc[i][j] = (f32x4){0.f, 0.f, 0.f, 0.f};

  for (int k0 = 0; k0 < 512; k0 += 64) {
    if (k0) __syncthreads();
#pragma unroll
    for (int i = 0; i < 4; ++i) {
      int idx = i * 256 + tid;
      int r = idx >> 3, cc = (idx & 7) * 8;
      float4 f0 = *(const float4*)&A[(size_t)(m0 + r) * 512 + k0 + cc];
      float4 f1 = *(const float4*)&A[(size_t)(m0 + r) * 512 + k0 + cc + 4];
      u32x4 pk;
      pk[0] = pkbf(f0.x, f0.y); pk[1] = pkbf(f0.z, f0.w);
      pk[2] = pkbf(f1.x, f1.y); pk[3] = pkbf(f1.z, f1.w);
      *(u32x4*)&As[r][cc] = pk;
      *(s16x8*)&Bs[r][cc] = *(const s16x8*)&Bt[(size_t)(n0 + r) * 512 + k0 + cc];
    }
    __syncthreads();
#pragma unroll
    for (int kk = 0; kk < 2; ++kk) {
      const int kb_ = kk * 32 + hi * 8;
      s16x8 af[4], bf[4];
#pragma unroll
      for (int mf = 0; mf < 4; ++mf) af[mf] = *(const s16x8*)&As[wr + mf * 16 + l16][kb_];
#pragma unroll
      for (int nf = 0; nf < 4; ++nf) bf[nf] = *(const s16x8*)&Bs[wc + nf * 16 + l16][kb_];
#pragma unroll
      for (int mf = 0; mf < 4; ++mf)
#pragma unroll
        for (int nf = 0; nf < 4; ++nf)
          acc[mf][nf] = __builtin_amdgcn_mfma_f32_16x16x32_bf16(af[mf], bf[nf], acc[mf][nf], 0, 0, 0);
    }
  }

#pragma unroll
  for (int mf = 0; mf < 4; ++mf)
#pragma unroll
    for (int nf = 0; nf < 4; ++nf)
#pragma unroll
      for (int i = 0; i < 4; ++i) {
        int row = m0 + wr + mf * 16 + hi * 4 + i;
        int col = n0 + wc + nf * 16 + l16;
        float val = acc[mf][nf][i] + bias[col];
        if (z == 0) val *= 0.18033688f;  // (1/sqrt(64)) * log2(e): exp2-domain scores
        int l = row >> 3, n = row & 7, hh = col >> 6, d = col & 63;
        if (z < 2)
          outp[(((size_t)(n * 8 + hh) * 1024 + l) << 6) + d] = f2bf(val);
        else
          outp[((size_t)(n * 8 + hh) * 64 + d) * 1024 + l] = f2bf(val);
      }
}

// ---------------- fused attention: QK^T -> top-k mask -> softmax -> PV ----------------
// grid (L/16, 64), 512 threads (8 waves), QBLK=16 -> 35KB LDS -> 4 blocks/CU.
// r9-proven structure (UNCHANGED from r12): truncated f2key keygen, Phase B =
// one row live per wave (fits 64-VGPR @ 8 waves/SIMD, no spill), clamped prefetch.
__global__ __launch_bounds__(512, 8) void attn_kernel(const u16* __restrict__ Qw,
                                                      const u16* __restrict__ Kw,
                                                      const u16* __restrict__ Vw,
                                                      const float* __restrict__ topk,
                                                      u16* __restrict__ ao) {
  __shared__ __align__(16) u16 scb[16 * 1024];  // 32KB: keys -> P (bf16), XOR-swizzled
  __shared__ __align__(16) u16 Qt[16][72];
  __shared__ float invs[16];
  const int tid = threadIdx.x, lane = tid & 63, wid = tid >> 6;
  const int l16 = lane & 15, hi = lane >> 4;
  const int mb = blockIdx.x, nh = blockIdx.y;

  const int kkeep = (int)(1024.f / (1.f + __expf(-topk[0])));

  // stage Q tile (16 x 64)
  if (tid < 256) {
    int r = tid >> 4, dc = (tid & 15) << 2;
    *(s16x4*)&Qt[r][dc] =
        *(const s16x4*)&Qw[((size_t)nh * 1024 + mb * 16 + r) * 64 + dc];
  }
  __syncthreads();

  // ---- Phase A: keys = key(QK^T), K prefetched one nf ahead. Wave w: s in [128w,128w+128).
  {
    const u16* Kb = Kw + (size_t)nh * 1024 * 64;
    s16x8 bq0 = *(const s16x8*)&Qt[l16][hi * 8];
    s16x8 bq1 = *(const s16x8*)&Qt[l16][32 + hi * 8];
    const int s0 = wid * 128;
    const size_t kbase = (size_t)(s0 + l16) * 64 + hi * 8;
    s16x8 c0 = *(const s16x8*)&Kb[kbase];
    s16x8 c1 = *(const s16x8*)&Kb[kbase + 32];
    char* rowq = (char*)scb + l16 * 2048;
    const int Xq = (l16 & 7) << 4;
#pragma unroll
    for (int nf = 0; nf < 8; ++nf) {
      const size_t nb = kbase + (size_t)(nf < 7 ? nf + 1 : nf) * 1024;  // clamped: always valid
      s16x8 n0_ = *(const s16x8*)&Kb[nb];
      s16x8 n1_ = *(const s16x8*)&Kb[nb + 32];
      f32x4 acc = {0.f, 0.f, 0.f, 0.f};
      acc = __builtin_amdgcn_mfma_f32_16x16x32_bf16(c0, bq0, acc, 0, 0, 0);
      acc = __builtin_amdgcn_mfma_f32_16x16x32_bf16(c1, bq1, acc, 0, 0, 0);
      u32 k0 = f2key(acc[0]) | (f2key(acc[1]) << 16);
      u32 k1 = f2key(acc[2]) | (f2key(acc[3]) << 16);
      int boff = (2 * (s0 + nf * 16 + 4 * hi)) ^ Xq;
      *(uint2*)(rowq + boff) = make_uint2(k0, k1);
      c0 = n0_; c1 = n1_;
    }
  }
  __syncthreads();

  // ---- Phase B: wave processes its 2 rows SEQUENTIALLY (1 row = 16 key VGPRs live).
  // Radix search: 1 v_cmp per 64-key count, scalar popcount/sum/select. P = exp2(v-T).
  for (int rp = 0; rp < 2; ++rp) {
    const int r = wid * 2 + rp;
    char* rb = (char*)scb + r * 2048;
    const int X = (r & 7) << 4;
    const int oa = (16 * lane) ^ X, ob = (16 * lane + 1024) ^ X;
    u32x4 qa = *(const u32x4*)(rb + oa), qb_ = *(const u32x4*)(rb + ob);
    u32 ka[16];
#pragma unroll
    for (int j = 0; j < 4; ++j) {
      ka[2 * j] = qa[j] & 0xFFFFu; ka[2 * j + 1] = qa[j] >> 16;
      ka[8 + 2 * j] = qb_[j] & 0xFFFFu; ka[9 + 2 * j] = qb_[j] >> 16;
    }
    u32 T = 0;
    for (int bit = 15; bit >= 0; --bit) {
      u32 c = T + (1u << bit);
      int n = 0;
#pragma unroll
      for (int j = 0; j < 16; ++j) n += __builtin_popcountll(cmp_ge(ka[j], c));
      T = (n >= kkeep) ? c : T;
    }
    const float tv = key2f(T);
    float s = 0.f;
    u32x4 wa, wb;
#pragma unroll
    for (int j = 0; j < 4; ++j) {
      float e0 = (ka[2 * j] >= T) ? __builtin_amdgcn_exp2f(key2f(ka[2 * j]) - tv) : 0.f;
      float e1 = (ka[2 * j + 1] >= T) ? __builtin_amdgcn_exp2f(key2f(ka[2 * j + 1]) - tv) : 0.f;
      float e2 = (ka[8 + 2 * j] >= T) ? __builtin_amdgcn_exp2f(key2f(ka[8 + 2 * j]) - tv) : 0.f;
      float e3 = (ka[9 + 2 * j] >= T) ? __builtin_amdgcn_exp2f(key2f(ka[9 + 2 * j]) - tv) : 0.f;
      s += e0 + e1 + e2 + e3;
      wa[j] = pkbf(e0, e1); wb[j] = pkbf(e2, e3);
    }
    *(u32x4*)(rb + oa) = wa; *(u32x4*)(rb + ob) = wb;
#pragma unroll
    for (int off = 1; off < 64; off <<= 1) s += __shfl_xor(s, off);
    if (lane == 0) invs[r] = __builtin_amdgcn_rcpf(s);
  }
  __syncthreads();

  // ---- Phase C: out = (P @ V) * inv, waves 0-3 only (wave w owns d [16w,16w+16)).
  if (wid < 4) {
    const u16* Vb = Vw + (size_t)nh * 64 * 1024;
    const int d0 = wid * 16;
    f32x4 oacc0 = {0.f, 0.f, 0.f, 0.f};
    f32x4 oacc1 = {0.f, 0.f, 0.f, 0.f};
    const char* Pbase = (const char*)scb + l16 * 2048;
    const int Xp = (l16 & 7) << 4;
    const size_t vbase = (size_t)(d0 + l16) * 1024 + hi * 8;
    s16x8 v0 = *(const s16x8*)&Vb[vbase];
    s16x8 v1 = *(const s16x8*)&Vb[vbase + 32];
#pragma unroll
    for (int ks = 0; ks < 32; ks += 2) {
      const int kss = ks < 30 ? ks + 2 : ks;  // clamped: always valid
      s16x8 nv0 = *(const s16x8*)&Vb[vbase + (size_t)kss * 32];
      s16x8 nv1 = *(const s16x8*)&Vb[vbase + (size_t)(kss + 1) * 32];
      s16x8 a0 = *(const s16x8*)(Pbase + ((ks * 64 + hi * 16) ^ Xp));
      s16x8 a1 = *(const s16x8*)(Pbase + (((ks + 1) * 64 + hi * 16) ^ Xp));
      oacc0 = __builtin_amdgcn_mfma_f32_16x16x32_bf16(a0, v0, oacc0, 0, 0, 0);
      oacc1 = __builtin_amdgcn_mfma_f32_16x16x32_bf16(a1, v1, oacc1, 0, 0, 0);
      v0 = nv0; v1 = nv1;
    }
    const int n = nh >> 3, hh = nh & 7;
#pragma unroll
    for (int i = 0; i < 4; ++i) {
      int l = mb * 16 + hi * 4 + i;
      int d = d0 + l16;
      float vv = (oacc0[i] + oacc1[i]) * invs[hi * 4 + i];
      ao[(size_t)(l * 8 + n) * 512 + d * 8 + hh] = f2bf(vv);
    }
  }
}

// ---------------- GEMM (BM=16, N=512, B direct from L2) + bias + resid + LayerNorm ----------------
// FIRST: out = LN1(ao@WoT + bo + q) -> srcb (bf16), K=512, residf=q
// else : out = LN2([w2p]@B2T4 + srcb) -> d_out (f32), K=256 (4 jc-partials)
template <bool FIRST>
__global__ __launch_bounds__(256, 2) void gemm_ln(const u16* __restrict__ A,
                                                  const u16* __restrict__ Bt,
                                                  const float* __restrict__ bias,
                                                  const float* __restrict__ residf,
                                                  const u16* __restrict__ residb,
                                                  const float* __restrict__ g,
                                                  const float* __restrict__ be,
                                                  float* __restrict__ outf,
                                                  u16* __restrict__ outb) {
  constexpr int K = FIRST ? 512 : 256;
  __shared__ __align__(16) u16 As[16][72];
  __shared__ float red_s[4][16];
  __shared__ float red_q[4][16];
  const int tid = threadIdx.x;
  const int lane = tid & 63, wid = tid >> 6;
  const int l16 = lane & 15, hi = lane >> 4;
  const int m0 = blockIdx.x * 16;
  const int wc = wid * 128;

  f32x4 acc[8];
#pragma unroll
  for (int nf = 0; nf < 8; ++nf) acc[nf] = (f32x4){0.f, 0.f, 0.f, 0.f};

  for (int k0 = 0; k0 < K; k0 += 64) {
    if (k0) __syncthreads();
    {
      int r = tid >> 4, c = (tid & 15) << 2;
      *(s16x4*)&As[r][c] = *(const s16x4*)&A[(size_t)(m0 + r) * K + k0 + c];
    }
    __syncthreads();
#pragma unroll
    for (int kk = 0; kk < 2; ++kk) {
      const int kb_ = kk * 32 + hi * 8;
      s16x8 a = *(const s16x8*)&As[l16][kb_];
#pragma unroll
      for (int nf = 0; nf < 8; ++nf) {
        s16x8 b = *(const s16x8*)&Bt[(size_t)(wc + nf * 16 + l16) * K + k0 + kb_];
        acc[nf] = __builtin_amdgcn_mfma_f32_16x16x32_bf16(a, b, acc[nf], 0, 0, 0);
      }
    }
  }

#pragma unroll
  for (int nf = 0; nf < 8; ++nf) {
    int col = wc + nf * 16 + l16;
#pragma unroll
    for (int i = 0; i < 4; ++i) {
      float v = acc[nf][i];
      int row = m0 + hi * 4 + i;
      if (FIRST) v += bias[col] + residf[(size_t)row * 512 + col];
      else v += bf2f(residb[(size_t)row * 512 + col]);
      acc[nf][i] = v;
    }
  }
  float s[4] = {0.f, 0.f, 0.f, 0.f}, q2[4] = {0.f, 0.f, 0.f, 0.f};
#pragma unroll
  for (int nf = 0; nf < 8; ++nf)
#pragma unroll
    for (int i = 0; i < 4; ++i) {
      s[i] += acc[nf][i];
      q2[i] += acc[nf][i] * acc[nf][i];
    }
#pragma unroll
  for (int i = 0; i < 4; ++i) {
#pragma unroll
    for (int off = 1; off < 16; off <<= 1) {
      s[i] += __shfl_xor(s[i], off);
      q2[i] += __shfl_xor(q2[i], off);
    }
  }
  if (l16 == 0) {
#pragma unroll
    for (int i = 0; i < 4; ++i) {
      red_s[wid][hi * 4 + i] = s[i];
      red_q[wid][hi * 4 + i] = q2[i];
    }
  }
  __syncthreads();
  float mean[4], rstd[4];
#pragma unroll
  for (int i = 0; i < 4; ++i) {
    int r = hi * 4 + i;
    float ms = red_s[0][r] + red_s[1][r] + red_s[2][r] + red_s[3][r];
    float mq = red_q[0][r] + red_q[1][r] + red_q[2][r] + red_q[3][r];
    mean[i] = ms * (1.f / 512.f);
    float var = mq * (1.f / 512.f) - mean[i] * mean[i];
    rstd[i] = rsqrtf(var + 1e-5f);
  }
#pragma unroll
  for (int nf = 0; nf < 8; ++nf) {
    int col = wc + nf * 16 + l16;
    float gv = g[col], bev = be[col];
#pragma unroll
    for (int i = 0; i < 4; ++i) {
      int row = m0 + hi * 4 + i;
      float y = (acc[nf][i] - mean[i]) * rstd[i] * gv + bev;
      if (FIRST) outb[(size_t)row * 512 + col] = f2bf(y);
      else outf[(size_t)row * 512 + col] = y;
    }
  }
}

// ---------------- fused low-rank FFN, jc-split: w2p[.,jcg*64+..] = relu(u@B1_jcg)@A2_jcg ----
// grid (256, 4): x = m-tile (BM=32), y = jc group (8 of 32 jc chunks each).
// u recomputed per group (0.5 GFLOP x3 redundant — negligible); critical path /4.
__global__ __launch_bounds__(256, 4) void ffn3(const u16* __restrict__ srcb,
                                               const u16* __restrict__ A1T,
                                               const u16* __restrict__ B1T,
                                               const u16* __restrict__ A2T,
                                               u16* __restrict__ w2p) {
  __shared__ __align__(16) u16 As[32][72];
  __shared__ __align__(16) u16 Bs[64][72];
  __shared__ __align__(16) u16 Us[32][72];
  __shared__ __align__(16) u16 B1s[64][72];
  __shared__ __align__(16) u16 A2s[64][72];
  __shared__ __align__(16) u16 Hs[32][72];
  const int tid = threadIdx.x;
  const int lane = tid & 63, wid = tid >> 6;
  const int l16 = lane & 15, hi = lane >> 4;
  const int m0 = blockIdx.x * 32;
  const int jcg = blockIdx.y;
  const int wm = (wid & 1) * 16, wn = (wid >> 1) * 32;

  f32x4 accu[2];
  accu[0] = (f32x4){0.f, 0.f, 0.f, 0.f};
  accu[1] = (f32x4){0.f, 0.f, 0.f, 0.f};
  for (int k0 = 0; k0 < 512; k0 += 64) {
    if (k0) __syncthreads();
    {
      int r = tid >> 3, c = (tid & 7) << 3;
      *(s16x8*)&As[r][c] = *(const s16x8*)&srcb[(size_t)(m0 + r) * 512 + k0 + c];
    }
#pragma unroll
    for (int i = 0; i < 2; ++i) {
      int idx = i * 256 + tid;
      int r = idx >> 3, c = (idx & 7) << 3;
      *(s16x8*)&Bs[r][c] = *(const s16x8*)&A1T[(size_t)r * 512 + k0 + c];
    }
    __syncthreads();
#pragma unroll
    for (int kk = 0; kk < 2; ++kk) {
      const int kb_ = kk * 32 + hi * 8;
      s16x8 a = *(const s16x8*)&As[wm + l16][kb_];
#pragma unroll
      for (int j = 0; j < 2; ++j) {
        s16x8 b = *(const s16x8*)&Bs[wn + j * 16 + l16][kb_];
        accu[j] = __builtin_amdgcn_mfma_f32_16x16x32_bf16(a, b, accu[j], 0, 0, 0);
      }
    }
  }
  __syncthreads();
#pragma unroll
  for (int j = 0; j < 2; ++j)
#pragma unroll
    for (int i = 0; i < 4; ++i)
      Us[wm + hi * 4 + i][wn + j * 16 + l16] = f2bf(accu[j][i]);

  f32x4 w2a[2];
  w2a[0] = (f32x4){0.f, 0.f, 0.f, 0.f};
  w2a[1] = (f32x4){0.f, 0.f, 0.f, 0.f};
  for (int jt = 0; jt < 8; ++jt) {
    const int jc = jcg * 8 + jt;
#pragma unroll
    for (int i = 0; i < 2; ++i) {
      int idx = i * 256 + tid;
      int r = idx >> 3, c = (idx & 7) << 3;
      *(s16x8*)&B1s[r][c] = *(const s16x8*)&B1T[(size_t)(jc * 64 + r) * 64 + c];
      *(s16x8*)&A2s[r][c] = *(const s16x8*)&A2T[(size_t)r * 2048 + jc * 64 + c];
    }
    __syncthreads();
    f32x4 ha[2];
    ha[0] = (f32x4){0.f, 0.f, 0.f, 0.f};
    ha[1] = (f32x4){0.f, 0.f, 0.f, 0.f};
#pragma unroll
    for (int kk = 0; kk < 2; ++kk) {
      const int kb_ = kk * 32 + hi * 8;
      s16x8 a = *(const s16x8*)&Us[wm + l16][kb_];
#pragma unroll
      for (int j = 0; j < 2; ++j) {
        s16x8 b = *(const s16x8*)&B1s[wn + j * 16 + l16][kb_];
        ha[j] = __builtin_amdgcn_mfma_f32_16x16x32_bf16(a, b, ha[j], 0, 0, 0);
      }
    }
#pragma unroll
    for (int j = 0; j < 2; ++j)
#pragma unroll
      for (int i = 0; i < 4; ++i)
        Hs[wm + hi * 4 + i][wn + j * 16 + l16] = f2bf(fmaxf(ha[j][i], 0.f));
    __syncthreads();
#pragma unroll
    for (int kk = 0; kk < 2; ++kk) {
      const int kb_ = kk * 32 + hi * 8;
      s16x8 a = *(const s16x8*)&Hs[wm + l16][kb_];
#pragma unroll
      for (int j = 0; j < 2; ++j) {
        s16x8 b = *(const s16x8*)&A2s[wn + j * 16 + l16][kb_];
        w2a[j] = __builtin_amdgcn_mfma_f32_16x16x32_bf16(a, b, w2a[j], 0, 0, 0);
      }
    }
    __syncthreads();
  }
#pragma unroll
  for (int j = 0; j < 2; ++j)
#pragma unroll
    for (int i = 0; i < 4; ++i)
      w2p[(size_t)(m0 + wm + hi * 4 + i) * 256 + jcg * 64 + wn + j * 16 + l16] = f2bf(w2a[j][i]);
}

// ---------------- host launch ----------------
extern "C" void kernel_launch(void* const* d_in, const int* in_sizes, int n_in,
                              void* d_out, int out_size, void* d_ws, size_t ws_size,
                              hipStream_t stream) {
  const float* q = (const float*)d_in[0];
  const float* k = (const float*)d_in[1];
  const float* v = (const float*)d_in[2];
  const float* Wq = (const float*)d_in[3];
  const float* bq = (const float*)d_in[4];
  const float* Wk = (const float*)d_in[5];
  const float* bk = (const float*)d_in[6];
  const float* Wv = (const float*)d_in[7];
  const float* bv = (const float*)d_in[8];
  const float* Wo = (const float*)d_in[9];
  const float* bo = (const float*)d_in[10];
  const float* topk = (const float*)d_in[11];
  const float* A1 = (const float*)d_in[12];
  const float* B1 = (const float*)d_in[13];
  const float* A2 = (const float*)d_in[14];
  const float* B2 = (const float*)d_in[15];
  const float* g1 = (const float*)d_in[16];
  const float* be1 = (const float*)d_in[17];
  const float* g2 = (const float*)d_in[18];
  const float* be2 = (const float*)d_in[19];

  char* ws = (char*)d_ws;
  constexpr size_t SZ_TOK_BF = (size_t)8192 * 512 * 2;
  constexpr size_t SZ_W_BF = (size_t)512 * 512 * 2;
  constexpr size_t O_QW = 0;
  constexpr size_t O_KW = O_QW + SZ_TOK_BF;
  constexpr size_t O_VW = O_KW + SZ_TOK_BF;
  constexpr size_t O_WQT = O_VW + SZ_TOK_BF;
  constexpr size_t O_WKT = O_WQT + SZ_W_BF;
  constexpr size_t O_WVT = O_WKT + SZ_W_BF;
  constexpr size_t O_WOT = O_WVT + SZ_W_BF;
  constexpr size_t O_A1T = O_WOT + SZ_W_BF;
  constexpr size_t O_B1T = O_A1T + 65536;
  constexpr size_t O_A2T = O_B1T + 262144;
  constexpr size_t O_B2T4 = O_A2T + 262144;               // 512 x 256 bf16
  constexpr size_t O_AO = O_B2T4 + 262144;
  constexpr size_t O_SRCB = O_AO + SZ_TOK_BF;
  constexpr size_t O_W2P = O_SRCB + SZ_TOK_BF;            // 8192 x 256 bf16

  u16* Qw_ = (u16*)(ws + O_QW);
  u16* Kw_ = (u16*)(ws + O_KW);
  u16* Vw_ = (u16*)(ws + O_VW);
  u16* WqT = (u16*)(ws + O_WQT);
  u16* WkT = (u16*)(ws + O_WKT);
  u16* WvT = (u16*)(ws + O_WVT);
  u16* WoT = (u16*)(ws + O_WOT);
  u16* A1T = (u16*)(ws + O_A1T);
  u16* B1T = (u16*)(ws + O_B1T);
  u16* A2T = (u16*)(ws + O_A2T);
  u16* B2T4 = (u16*)(ws + O_B2T4);
  u16* ao = (u16*)(ws + O_AO);
  u16* srcb = (u16*)(ws + O_SRCB);
  u16* w2p = (u16*)(ws + O_W2P);

  // 1) weight transposes only (B2 -> B2T4, replicated 4x along K)
  prep_w<<<336, 256, 0, stream>>>(Wq, Wk, Wv, Wo, A1, B1, A2, B2,
                                  WqT, WkT, WvT, WoT, A1T, B1T, A2T, B2T4);

  // 2) QKV projections straight from f32 inputs (Q in exp2 domain)
  qkv_fused<<<dim3(4, 64, 3), 256, 0, stream>>>(q, k, v, WqT, WkT, WvT,
                                                bq, bk, bv, Qw_, Kw_, Vw_);

  // 3) fused attention (r12-proven, unchanged)
  attn_kernel<<<dim3(64, 64), 512, 0, stream>>>(Qw_, Kw_, Vw_, topk, ao);

  // 4) Wo + bias + residual(q) + LN1 -> srcb
  gemm_ln<true><<<512, 256, 0, stream>>>(ao, WoT, bo, q, nullptr, g1, be1, nullptr, srcb);

  // 5) fused FFN inner, jc-split x4: w2p = partials of relu(srcb@A1@B1)@A2
  ffn3<<<dim3(256, 4), 256, 0, stream>>>(srcb, A1T, B1T, A2T, w2p);

  // 6) [w2p] @ B2T4 (sums the 4 partials) + residual(srcb) + LN2 -> d_out
  gemm_ln<false><<<512, 256, 0, stream>>>(w2p, B2T4, nullptr, nullptr, srcb, g2, be2,
                                          (float*)d_out, nullptr);
}

// Round 14
// 255.310 us; speedup vs baseline: 1.0205x; 1.0205x over previous
//
#include <hip/hip_runtime.h>

typedef unsigned short u16;
typedef unsigned int u32;
typedef unsigned long long u64;
using s16x8 = __attribute__((ext_vector_type(8))) short;
using s16x4 = __attribute__((ext_vector_type(4))) short;
using u16x4 = __attribute__((ext_vector_type(4))) unsigned short;
using u32x4 = __attribute__((ext_vector_type(4))) unsigned int;
using f32x4 = __attribute__((ext_vector_type(4))) float;

__device__ __forceinline__ u16 f2bf(float f) {
  unsigned int u = __float_as_uint(f);
  u += 0x7FFFu + ((u >> 16) & 1u);
  return (u16)(u >> 16);
}
__device__ __forceinline__ float bf2f(u16 b) {
  return __uint_as_float(((u32)b) << 16);
}
__device__ __forceinline__ u32 pkbf(float a, float b) {
  u32 r;
  asm("v_cvt_pk_bf16_f32 %0, %1, %2" : "=v"(r) : "v"(a), "v"(b));
  return r;
}
// single v_cmp producing a 64-bit lane mask in SGPRs: key >= cand
__device__ __forceinline__ u64 cmp_ge(u32 key, u32 cand) {
  u64 m;
  asm("v_cmp_le_u32 %0, %1, %2" : "=s"(m) : "s"(cand), "v"(key));
  return m;
}
// monotone 16-bit key from f32 (sign-flip trick, truncated) — r9-proven
__device__ __forceinline__ u32 f2key(float f) {
  u32 u = __float_as_uint(f);
  u32 flip = (u32)((int)u >> 31) | 0x80000000u;
  return (u ^ flip) >> 16;
}
// inverse: 16-bit key -> f32 (truncated value)
__device__ __forceinline__ float key2f(u32 k) {
  u32 t = k << 16;
  u32 msk = ((int)t < 0) ? 0x80000000u : 0xFFFF0000u;
  return __uint_as_float(t ^ msk);
}

// ---------------- prep: weight transposes only (64x64 LDS tiles) ----------------
__global__ __launch_bounds__(256) void prep_w(
    const float* __restrict__ Wq, const float* __restrict__ Wk, const float* __restrict__ Wv,
    const float* __restrict__ Wo, const float* __restrict__ A1, const float* __restrict__ B1,
    const float* __restrict__ A2, const float* __restrict__ B2,
    u16* __restrict__ WqT, u16* __restrict__ WkT, u16* __restrict__ WvT, u16* __restrict__ WoT,
    u16* __restrict__ A1T, u16* __restrict__ B1T, u16* __restrict__ A2T, u16* __restrict__ B2T) {
  __shared__ u16 t[64][68];
  int b = blockIdx.x, tid = threadIdx.x;
  const float* src; u16* dst; int base, R, C;
  if (b < 64)        { src = Wq; dst = WqT; base = 0;   R = 512;  C = 512; }
  else if (b < 128)  { src = Wk; dst = WkT; base = 64;  R = 512;  C = 512; }
  else if (b < 192)  { src = Wv; dst = WvT; base = 128; R = 512;  C = 512; }
  else if (b < 256)  { src = Wo; dst = WoT; base = 192; R = 512;  C = 512; }
  else if (b < 264)  { src = A1; dst = A1T; base = 256; R = 512;  C = 64;  }
  else if (b < 296)  { src = B1; dst = B1T; base = 264; R = 64;   C = 2048;}
  else if (b < 328)  { src = A2; dst = A2T; base = 296; R = 2048; C = 64;  }
  else               { src = B2; dst = B2T; base = 328; R = 64;   C = 512; }
  int ti = b - base;
  int tpr = C >> 6;
  int r0 = (ti / tpr) * 64, c0 = (ti % tpr) * 64;
#pragma unroll
  for (int i = 0; i < 4; ++i) {
    int r = i * 16 + (tid >> 4), c = (tid & 15) * 4;
    float4 f = *(const float4*)&src[(size_t)(r0 + r) * C + c0 + c];
    t[r][c] = f2bf(f.x); t[r][c + 1] = f2bf(f.y);
    t[r][c + 2] = f2bf(f.z); t[r][c + 3] = f2bf(f.w);
  }
  __syncthreads();
#pragma unroll
  for (int i = 0; i < 4; ++i) {
    int cc = i * 16 + (tid >> 4), rr = (tid & 15) * 4;
    u16x4 o;
    o[0] = t[rr][cc]; o[1] = t[rr + 1][cc]; o[2] = t[rr + 2][cc]; o[3] = t[rr + 3][cc];
    *(u16x4*)&dst[(size_t)(c0 + cc) * R + r0 + rr] = o;
  }
}

// ---------------- fused QKV projection from f32 inputs: 128x128 tiles, grid (4,64,3) ----
// z=0: Q (scaled 0.125*log2e, scatter [nh][l][d]); z=1: K ([nh][l][d]); z=2: V ([nh][d][l]).
__global__ __launch_bounds__(256, 4) void qkv_fused(
    const float* __restrict__ q, const float* __restrict__ k, const float* __restrict__ v,
    const u16* __restrict__ WqT, const u16* __restrict__ WkT, const u16* __restrict__ WvT,
    const float* __restrict__ bq, const float* __restrict__ bk, const float* __restrict__ bv,
    u16* __restrict__ Qw, u16* __restrict__ Kw, u16* __restrict__ Vw) {
  __shared__ __align__(16) u16 As[128][72];
  __shared__ __align__(16) u16 Bs[128][72];
  const int z = blockIdx.z;
  const float* A = z == 0 ? q : (z == 1 ? k : v);
  const u16* Bt = z == 0 ? WqT : (z == 1 ? WkT : WvT);
  const float* bias = z == 0 ? bq : (z == 1 ? bk : bv);
  u16* outp = z == 0 ? Qw : (z == 1 ? Kw : Vw);

  const int tid = threadIdx.x;
  const int m0 = blockIdx.y * 128, n0 = blockIdx.x * 128;
  const int lane = tid & 63, wid = tid >> 6;
  const int l16 = lane & 15, hi = lane >> 4;
  const int wr = (wid >> 1) * 64, wc = (wid & 1) * 64;

  f32x4 acc[4][4];
#pragma unroll
  for (int i = 0; i < 4; ++i)
#pragma unroll
    for (int j = 0; j < 4; ++j) acc[i][j] = (f32x4){0.f, 0.f, 0.f, 0.f};

  for (int k0 = 0; k0 < 512; k0 += 64) {
    if (k0) __syncthreads();
#pragma unroll
    for (int i = 0; i < 4; ++i) {
      int idx = i * 256 + tid;
      int r = idx >> 3, cc = (idx & 7) * 8;
      float4 f0 = *(const float4*)&A[(size_t)(m0 + r) * 512 + k0 + cc];
      float4 f1 = *(const float4*)&A[(size_t)(m0 + r) * 512 + k0 + cc + 4];
      u32x4 pk;
      pk[0] = pkbf(f0.x, f0.y); pk[1] = pkbf(f0.z, f0.w);
      pk[2] = pkbf(f1.x, f1.y); pk[3] = pkbf(f1.z, f1.w);
      *(u32x4*)&As[r][cc] = pk;
      *(s16x8*)&Bs[r][cc] = *(const s16x8*)&Bt[(size_t)(n0 + r) * 512 + k0 + cc];
    }
    __syncthreads();
#pragma unroll
    for (int kk = 0; kk < 2; ++kk) {
      const int kb_ = kk * 32 + hi * 8;
      s16x8 af[4], bf[4];
#pragma unroll
      for (int mf = 0; mf < 4; ++mf) af[mf] = *(const s16x8*)&As[wr + mf * 16 + l16][kb_];
#pragma unroll
      for (int nf = 0; nf < 4; ++nf) bf[nf] = *(const s16x8*)&Bs[wc + nf * 16 + l16][kb_];
#pragma unroll
      for (int mf = 0; mf < 4; ++mf)
#pragma unroll
        for (int nf = 0; nf < 4; ++nf)
          acc[mf][nf] = __builtin_amdgcn_mfma_f32_16x16x32_bf16(af[mf], bf[nf], acc[mf][nf], 0, 0, 0);
    }
  }

#pragma unroll
  for (int mf = 0; mf < 4; ++mf)
#pragma unroll
    for (int nf = 0; nf < 4; ++nf)
#pragma unroll
      for (int i = 0; i < 4; ++i) {
        int row = m0 + wr + mf * 16 + hi * 4 + i;
        int col = n0 + wc + nf * 16 + l16;
        float val = acc[mf][nf][i] + bias[col];
        if (z == 0) val *= 0.18033688f;  // (1/sqrt(64)) * log2(e): exp2-domain scores
        int l = row >> 3, n = row & 7, hh = col >> 6, d = col & 63;
        if (z < 2)
          outp[(((size_t)(n * 8 + hh) * 1024 + l) << 6) + d] = f2bf(val);
        else
          outp[((size_t)(n * 8 + hh) * 64 + d) * 1024 + l] = f2bf(val);
      }
}

// ---------------- fused attention: QK^T -> top-k mask -> softmax -> PV ----------------
// grid (L/16, 64), 512 threads (8 waves), QBLK=16 -> 35KB LDS -> 4 blocks/CU.
// r12-proven, UNCHANGED.
__global__ __launch_bounds__(512, 8) void attn_kernel(const u16* __restrict__ Qw,
                                                      const u16* __restrict__ Kw,
                                                      const u16* __restrict__ Vw,
                                                      const float* __restrict__ topk,
                                                      u16* __restrict__ ao) {
  __shared__ __align__(16) u16 scb[16 * 1024];  // 32KB: keys -> P (bf16), XOR-swizzled
  __shared__ __align__(16) u16 Qt[16][72];
  __shared__ float invs[16];
  const int tid = threadIdx.x, lane = tid & 63, wid = tid >> 6;
  const int l16 = lane & 15, hi = lane >> 4;
  const int mb = blockIdx.x, nh = blockIdx.y;

  const int kkeep = (int)(1024.f / (1.f + __expf(-topk[0])));

  // stage Q tile (16 x 64)
  if (tid < 256) {
    int r = tid >> 4, dc = (tid & 15) << 2;
    *(s16x4*)&Qt[r][dc] =
        *(const s16x4*)&Qw[((size_t)nh * 1024 + mb * 16 + r) * 64 + dc];
  }
  __syncthreads();

  // ---- Phase A: keys = key(QK^T), K prefetched one nf ahead. Wave w: s in [128w,128w+128).
  {
    const u16* Kb = Kw + (size_t)nh * 1024 * 64;
    s16x8 bq0 = *(const s16x8*)&Qt[l16][hi * 8];
    s16x8 bq1 = *(const s16x8*)&Qt[l16][32 + hi * 8];
    const int s0 = wid * 128;
    const size_t kbase = (size_t)(s0 + l16) * 64 + hi * 8;
    s16x8 c0 = *(const s16x8*)&Kb[kbase];
    s16x8 c1 = *(const s16x8*)&Kb[kbase + 32];
    char* rowq = (char*)scb + l16 * 2048;
    const int Xq = (l16 & 7) << 4;
#pragma unroll
    for (int nf = 0; nf < 8; ++nf) {
      const size_t nb = kbase + (size_t)(nf < 7 ? nf + 1 : nf) * 1024;  // clamped: always valid
      s16x8 n0_ = *(const s16x8*)&Kb[nb];
      s16x8 n1_ = *(const s16x8*)&Kb[nb + 32];
      f32x4 acc = {0.f, 0.f, 0.f, 0.f};
      acc = __builtin_amdgcn_mfma_f32_16x16x32_bf16(c0, bq0, acc, 0, 0, 0);
      acc = __builtin_amdgcn_mfma_f32_16x16x32_bf16(c1, bq1, acc, 0, 0, 0);
      u32 k0 = f2key(acc[0]) | (f2key(acc[1]) << 16);
      u32 k1 = f2key(acc[2]) | (f2key(acc[3]) << 16);
      int boff = (2 * (s0 + nf * 16 + 4 * hi)) ^ Xq;
      *(uint2*)(rowq + boff) = make_uint2(k0, k1);
      c0 = n0_; c1 = n1_;
    }
  }
  __syncthreads();

  // ---- Phase B: wave processes its 2 rows SEQUENTIALLY (1 row = 16 key VGPRs live).
  for (int rp = 0; rp < 2; ++rp) {
    const int r = wid * 2 + rp;
    char* rb = (char*)scb + r * 2048;
    const int X = (r & 7) << 4;
    const int oa = (16 * lane) ^ X, ob = (16 * lane + 1024) ^ X;
    u32x4 qa = *(const u32x4*)(rb + oa), qb_ = *(const u32x4*)(rb + ob);
    u32 ka[16];
#pragma unroll
    for (int j = 0; j < 4; ++j) {
      ka[2 * j] = qa[j] & 0xFFFFu; ka[2 * j + 1] = qa[j] >> 16;
      ka[8 + 2 * j] = qb_[j] & 0xFFFFu; ka[9 + 2 * j] = qb_[j] >> 16;
    }
    u32 T = 0;
    for (int bit = 15; bit >= 0; --bit) {
      u32 c = T + (1u << bit);
      int n = 0;
#pragma unroll
      for (int j = 0; j < 16; ++j) n += __builtin_popcountll(cmp_ge(ka[j], c));
      T = (n >= kkeep) ? c : T;
    }
    const float tv = key2f(T);
    float s = 0.f;
    u32x4 wa, wb;
#pragma unroll
    for (int j = 0; j < 4; ++j) {
      float e0 = (ka[2 * j] >= T) ? __builtin_amdgcn_exp2f(key2f(ka[2 * j]) - tv) : 0.f;
      float e1 = (ka[2 * j + 1] >= T) ? __builtin_amdgcn_exp2f(key2f(ka[2 * j + 1]) - tv) : 0.f;
      float e2 = (ka[8 + 2 * j] >= T) ? __builtin_amdgcn_exp2f(key2f(ka[8 + 2 * j]) - tv) : 0.f;
      float e3 = (ka[9 + 2 * j] >= T) ? __builtin_amdgcn_exp2f(key2f(ka[9 + 2 * j]) - tv) : 0.f;
      s += e0 + e1 + e2 + e3;
      wa[j] = pkbf(e0, e1); wb[j] = pkbf(e2, e3);
    }
    *(u32x4*)(rb + oa) = wa; *(u32x4*)(rb + ob) = wb;
#pragma unroll
    for (int off = 1; off < 64; off <<= 1) s += __shfl_xor(s, off);
    if (lane == 0) invs[r] = __builtin_amdgcn_rcpf(s);
  }
  __syncthreads();

  // ---- Phase C: out = (P @ V) * inv, waves 0-3 only (wave w owns d [16w,16w+16)).
  if (wid < 4) {
    const u16* Vb = Vw + (size_t)nh * 64 * 1024;
    const int d0 = wid * 16;
    f32x4 oacc0 = {0.f, 0.f, 0.f, 0.f};
    f32x4 oacc1 = {0.f, 0.f, 0.f, 0.f};
    const char* Pbase = (const char*)scb + l16 * 2048;
    const int Xp = (l16 & 7) << 4;
    const size_t vbase = (size_t)(d0 + l16) * 1024 + hi * 8;
    s16x8 v0 = *(const s16x8*)&Vb[vbase];
    s16x8 v1 = *(const s16x8*)&Vb[vbase + 32];
#pragma unroll
    for (int ks = 0; ks < 32; ks += 2) {
      const int kss = ks < 30 ? ks + 2 : ks;  // clamped: always valid
      s16x8 nv0 = *(const s16x8*)&Vb[vbase + (size_t)kss * 32];
      s16x8 nv1 = *(const s16x8*)&Vb[vbase + (size_t)(kss + 1) * 32];
      s16x8 a0 = *(const s16x8*)(Pbase + ((ks * 64 + hi * 16) ^ Xp));
      s16x8 a1 = *(const s16x8*)(Pbase + (((ks + 1) * 64 + hi * 16) ^ Xp));
      oacc0 = __builtin_amdgcn_mfma_f32_16x16x32_bf16(a0, v0, oacc0, 0, 0, 0);
      oacc1 = __builtin_amdgcn_mfma_f32_16x16x32_bf16(a1, v1, oacc1, 0, 0, 0);
      v0 = nv0; v1 = nv1;
    }
    const int n = nh >> 3, hh = nh & 7;
#pragma unroll
    for (int i = 0; i < 4; ++i) {
      int l = mb * 16 + hi * 4 + i;
      int d = d0 + l16;
      float vv = (oacc0[i] + oacc1[i]) * invs[hi * 4 + i];
      ao[(size_t)(l * 8 + n) * 512 + d * 8 + hh] = f2bf(vv);
    }
  }
}

// ---------------- GEMM (BM=16, N=512, K=512) + bias + resid(q,f32) + LayerNorm1 -> bf16 ----
__global__ __launch_bounds__(256, 2) void gemm_ln1(const u16* __restrict__ A,
                                                   const u16* __restrict__ Bt,
                                                   const float* __restrict__ bias,
                                                   const float* __restrict__ residf,
                                                   const float* __restrict__ g,
                                                   const float* __restrict__ be,
                                                   u16* __restrict__ outb) {
  constexpr int K = 512;
  __shared__ __align__(16) u16 As[16][72];
  __shared__ float red_s[4][16];
  __shared__ float red_q[4][16];
  const int tid = threadIdx.x;
  const int lane = tid & 63, wid = tid >> 6;
  const int l16 = lane & 15, hi = lane >> 4;
  const int m0 = blockIdx.x * 16;
  const int wc = wid * 128;

  f32x4 acc[8];
#pragma unroll
  for (int nf = 0; nf < 8; ++nf) acc[nf] = (f32x4){0.f, 0.f, 0.f, 0.f};

  for (int k0 = 0; k0 < K; k0 += 64) {
    if (k0) __syncthreads();
    {
      int r = tid >> 4, c = (tid & 15) << 2;
      *(s16x4*)&As[r][c] = *(const s16x4*)&A[(size_t)(m0 + r) * K + k0 + c];
    }
    __syncthreads();
#pragma unroll
    for (int kk = 0; kk < 2; ++kk) {
      const int kb_ = kk * 32 + hi * 8;
      s16x8 a = *(const s16x8*)&As[l16][kb_];
#pragma unroll
      for (int nf = 0; nf < 8; ++nf) {
        s16x8 b = *(const s16x8*)&Bt[(size_t)(wc + nf * 16 + l16) * K + k0 + kb_];
        acc[nf] = __builtin_amdgcn_mfma_f32_16x16x32_bf16(a, b, acc[nf], 0, 0, 0);
      }
    }
  }

#pragma unroll
  for (int nf = 0; nf < 8; ++nf) {
    int col = wc + nf * 16 + l16;
#pragma unroll
    for (int i = 0; i < 4; ++i) {
      int row = m0 + hi * 4 + i;
      acc[nf][i] += bias[col] + residf[(size_t)row * 512 + col];
    }
  }
  float s[4] = {0.f, 0.f, 0.f, 0.f}, q2[4] = {0.f, 0.f, 0.f, 0.f};
#pragma unroll
  for (int nf = 0; nf < 8; ++nf)
#pragma unroll
    for (int i = 0; i < 4; ++i) {
      s[i] += acc[nf][i];
      q2[i] += acc[nf][i] * acc[nf][i];
    }
#pragma unroll
  for (int i = 0; i < 4; ++i) {
#pragma unroll
    for (int off = 1; off < 16; off <<= 1) {
      s[i] += __shfl_xor(s[i], off);
      q2[i] += __shfl_xor(q2[i], off);
    }
  }
  if (l16 == 0) {
#pragma unroll
    for (int i = 0; i < 4; ++i) {
      red_s[wid][hi * 4 + i] = s[i];
      red_q[wid][hi * 4 + i] = q2[i];
    }
  }
  __syncthreads();
  float mean[4], rstd[4];
#pragma unroll
  for (int i = 0; i < 4; ++i) {
    int r = hi * 4 + i;
    float ms = red_s[0][r] + red_s[1][r] + red_s[2][r] + red_s[3][r];
    float mq = red_q[0][r] + red_q[1][r] + red_q[2][r] + red_q[3][r];
    mean[i] = ms * (1.f / 512.f);
    float var = mq * (1.f / 512.f) - mean[i] * mean[i];
    rstd[i] = rsqrtf(var + 1e-5f);
  }
#pragma unroll
  for (int nf = 0; nf < 8; ++nf) {
    int col = wc + nf * 16 + l16;
    float gv = g[col], bev = be[col];
#pragma unroll
    for (int i = 0; i < 4; ++i) {
      int row = m0 + hi * 4 + i;
      float y = (acc[nf][i] - mean[i]) * rstd[i] * gv + bev;
      outb[(size_t)row * 512 + col] = f2bf(y);
    }
  }
}

// ---------------- fused low-rank FFN + B2 + residual + LN2: one kernel ----------------
// grid(256), 256 threads, BM=32.
// stage1: u = srcb@A1T. stage2: w2 = sum_jc relu(u@B1c)@A2c (tile 32x64, reg->LDS).
// stage3: out32x512 = w2@B2T + srcb; LN2; write d_out (f32). No w2 global round-trip.
__global__ __launch_bounds__(256, 2) void ffn3_ln(const u16* __restrict__ srcb,
                                                  const u16* __restrict__ A1T,
                                                  const u16* __restrict__ B1T,
                                                  const u16* __restrict__ A2T,
                                                  const u16* __restrict__ B2T,
                                                  const float* __restrict__ g,
                                                  const float* __restrict__ be,
                                                  float* __restrict__ outf) {
  __shared__ __align__(16) u16 As[32][72];   // srcb staging; later the w2 tile
  __shared__ __align__(16) u16 Bs[64][72];
  __shared__ __align__(16) u16 Us[32][72];
  __shared__ __align__(16) u16 B1s[64][72];
  __shared__ __align__(16) u16 A2s[64][72];
  __shared__ __align__(16) u16 Hs[32][72];
  __shared__ float red_s[4][32];
  __shared__ float red_q[4][32];
  const int tid = threadIdx.x;
  const int lane = tid & 63, wid = tid >> 6;
  const int l16 = lane & 15, hi = lane >> 4;
  const int m0 = blockIdx.x * 32;
  const int wm = (wid & 1) * 16, wn = (wid >> 1) * 32;

  // ---- stage 1: u(32x64) = srcb_tile @ A1T^T ----
  f32x4 accu[2];
  accu[0] = (f32x4){0.f, 0.f, 0.f, 0.f};
  accu[1] = (f32x4){0.f, 0.f, 0.f, 0.f};
  for (int k0 = 0; k0 < 512; k0 += 64) {
    if (k0) __syncthreads();
    {
      int r = tid >> 3, c = (tid & 7) << 3;
      *(s16x8*)&As[r][c] = *(const s16x8*)&srcb[(size_t)(m0 + r) * 512 + k0 + c];
    }
#pragma unroll
    for (int i = 0; i < 2; ++i) {
      int idx = i * 256 + tid;
      int r = idx >> 3, c = (idx & 7) << 3;
      *(s16x8*)&Bs[r][c] = *(const s16x8*)&A1T[(size_t)r * 512 + k0 + c];
    }
    __syncthreads();
#pragma unroll
    for (int kk = 0; kk < 2; ++kk) {
      const int kb_ = kk * 32 + hi * 8;
      s16x8 a = *(const s16x8*)&As[wm + l16][kb_];
#pragma unroll
      for (int j = 0; j < 2; ++j) {
        s16x8 b = *(const s16x8*)&Bs[wn + j * 16 + l16][kb_];
        accu[j] = __builtin_amdgcn_mfma_f32_16x16x32_bf16(a, b, accu[j], 0, 0, 0);
      }
    }
  }
  __syncthreads();
#pragma unroll
  for (int j = 0; j < 2; ++j)
#pragma unroll
    for (int i = 0; i < 4; ++i)
      Us[wm + hi * 4 + i][wn + j * 16 + l16] = f2bf(accu[j][i]);

  // ---- stage 2: w2(32x64) = sum over 32 jc chunks of relu(u@B1c)@A2c ----
  f32x4 w2a[2];
  w2a[0] = (f32x4){0.f, 0.f, 0.f, 0.f};
  w2a[1] = (f32x4){0.f, 0.f, 0.f, 0.f};
  for (int jc = 0; jc < 32; ++jc) {
#pragma unroll
    for (int i = 0; i < 2; ++i) {
      int idx = i * 256 + tid;
      int r = idx >> 3, c = (idx & 7) << 3;
      *(s16x8*)&B1s[r][c] = *(const s16x8*)&B1T[(size_t)(jc * 64 + r) * 64 + c];
      *(s16x8*)&A2s[r][c] = *(const s16x8*)&A2T[(size_t)r * 2048 + jc * 64 + c];
    }
    __syncthreads();
    f32x4 ha[2];
    ha[0] = (f32x4){0.f, 0.f, 0.f, 0.f};
    ha[1] = (f32x4){0.f, 0.f, 0.f, 0.f};
#pragma unroll
    for (int kk = 0; kk < 2; ++kk) {
      const int kb_ = kk * 32 + hi * 8;
      s16x8 a = *(const s16x8*)&Us[wm + l16][kb_];
#pragma unroll
      for (int j = 0; j < 2; ++j) {
        s16x8 b = *(const s16x8*)&B1s[wn + j * 16 + l16][kb_];
        ha[j] = __builtin_amdgcn_mfma_f32_16x16x32_bf16(a, b, ha[j], 0, 0, 0);
      }
    }
#pragma unroll
    for (int j = 0; j < 2; ++j)
#pragma unroll
      for (int i = 0; i < 4; ++i)
        Hs[wm + hi * 4 + i][wn + j * 16 + l16] = f2bf(fmaxf(ha[j][i], 0.f));
    __syncthreads();
#pragma unroll
    for (int kk = 0; kk < 2; ++kk) {
      const int kb_ = kk * 32 + hi * 8;
      s16x8 a = *(const s16x8*)&Hs[wm + l16][kb_];
#pragma unroll
      for (int j = 0; j < 2; ++j) {
        s16x8 b = *(const s16x8*)&A2s[wn + j * 16 + l16][kb_];
        w2a[j] = __builtin_amdgcn_mfma_f32_16x16x32_bf16(a, b, w2a[j], 0, 0, 0);
      }
    }
    __syncthreads();
  }

  // ---- stage 3: w2 tile -> LDS (reuse As); out = w2@B2T + srcb; LN2 -> d_out ----
#pragma unroll
  for (int j = 0; j < 2; ++j)
#pragma unroll
    for (int i = 0; i < 4; ++i)
      As[wm + hi * 4 + i][wn + j * 16 + l16] = f2bf(w2a[j][i]);
  __syncthreads();

  const int wc = wid * 128;
  f32x4 acc[2][8];
#pragma unroll
  for (int mf = 0; mf < 2; ++mf)
#pragma unroll
    for (int nf = 0; nf < 8; ++nf) acc[mf][nf] = (f32x4){0.f, 0.f, 0.f, 0.f};
#pragma unroll
  for (int kk = 0; kk < 2; ++kk) {
    const int kb_ = kk * 32 + hi * 8;
    s16x8 a0 = *(const s16x8*)&As[l16][kb_];
    s16x8 a1 = *(const s16x8*)&As[16 + l16][kb_];
#pragma unroll
    for (int nf = 0; nf < 8; ++nf) {
      s16x8 b = *(const s16x8*)&B2T[(size_t)(wc + nf * 16 + l16) * 64 + kb_];
      acc[0][nf] = __builtin_amdgcn_mfma_f32_16x16x32_bf16(a0, b, acc[0][nf], 0, 0, 0);
      acc[1][nf] = __builtin_amdgcn_mfma_f32_16x16x32_bf16(a1, b, acc[1][nf], 0, 0, 0);
    }
  }
  // residual + per-row partial sums
  float s_[2][4], q2_[2][4];
#pragma unroll
  for (int mf = 0; mf < 2; ++mf)
#pragma unroll
    for (int i = 0; i < 4; ++i) { s_[mf][i] = 0.f; q2_[mf][i] = 0.f; }
#pragma unroll
  for (int mf = 0; mf < 2; ++mf)
#pragma unroll
    for (int nf = 0; nf < 8; ++nf) {
      int col = wc + nf * 16 + l16;
#pragma unroll
      for (int i = 0; i < 4; ++i) {
        int row = m0 + mf * 16 + hi * 4 + i;
        float v = acc[mf][nf][i] + bf2f(srcb[(size_t)row * 512 + col]);
        acc[mf][nf][i] = v;
        s_[mf][i] += v;
        q2_[mf][i] += v * v;
      }
    }
#pragma unroll
  for (int mf = 0; mf < 2; ++mf)
#pragma unroll
    for (int i = 0; i < 4; ++i) {
#pragma unroll
      for (int off = 1; off < 16; off <<= 1) {
        s_[mf][i] += __shfl_xor(s_[mf][i], off);
        q2_[mf][i] += __shfl_xor(q2_[mf][i], off);
      }
    }
  if (l16 == 0) {
#pragma unroll
    for (int mf = 0; mf < 2; ++mf)
#pragma unroll
      for (int i = 0; i < 4; ++i) {
        red_s[wid][mf * 16 + hi * 4 + i] = s_[mf][i];
        red_q[wid][mf * 16 + hi * 4 + i] = q2_[mf][i];
      }
  }
  __syncthreads();
  float mean[2][4], rstd[2][4];
#pragma unroll
  for (int mf = 0; mf < 2; ++mf)
#pragma unroll
    for (int i = 0; i < 4; ++i) {
      int r = mf * 16 + hi * 4 + i;
      float ms = red_s[0][r] + red_s[1][r] + red_s[2][r] + red_s[3][r];
      float mq = red_q[0][r] + red_q[1][r] + red_q[2][r] + red_q[3][r];
      mean[mf][i] = ms * (1.f / 512.f);
      float var = mq * (1.f / 512.f) - mean[mf][i] * mean[mf][i];
      rstd[mf][i] = rsqrtf(var + 1e-5f);
    }
#pragma unroll
  for (int mf = 0; mf < 2; ++mf)
#pragma unroll
    for (int nf = 0; nf < 8; ++nf) {
      int col = wc + nf * 16 + l16;
      float gv = g[col], bev = be[col];
#pragma unroll
      for (int i = 0; i < 4; ++i) {
        int row = m0 + mf * 16 + hi * 4 + i;
        float y = (acc[mf][nf][i] - mean[mf][i]) * rstd[mf][i] * gv + bev;
        outf[(size_t)row * 512 + col] = y;
      }
    }
}

// ---------------- host launch ----------------
extern "C" void kernel_launch(void* const* d_in, const int* in_sizes, int n_in,
                              void* d_out, int out_size, void* d_ws, size_t ws_size,
                              hipStream_t stream) {
  const float* q = (const float*)d_in[0];
  const float* k = (const float*)d_in[1];
  const float* v = (const float*)d_in[2];
  const float* Wq = (const float*)d_in[3];
  const float* bq = (const float*)d_in[4];
  const float* Wk = (const float*)d_in[5];
  const float* bk = (const float*)d_in[6];
  const float* Wv = (const float*)d_in[7];
  const float* bv = (const float*)d_in[8];
  const float* Wo = (const float*)d_in[9];
  const float* bo = (const float*)d_in[10];
  const float* topk = (const float*)d_in[11];
  const float* A1 = (const float*)d_in[12];
  const float* B1 = (const float*)d_in[13];
  const float* A2 = (const float*)d_in[14];
  const float* B2 = (const float*)d_in[15];
  const float* g1 = (const float*)d_in[16];
  const float* be1 = (const float*)d_in[17];
  const float* g2 = (const float*)d_in[18];
  const float* be2 = (const float*)d_in[19];

  char* ws = (char*)d_ws;
  constexpr size_t SZ_TOK_BF = (size_t)8192 * 512 * 2;
  constexpr size_t SZ_W_BF = (size_t)512 * 512 * 2;
  constexpr size_t O_QW = 0;
  constexpr size_t O_KW = O_QW + SZ_TOK_BF;
  constexpr size_t O_VW = O_KW + SZ_TOK_BF;
  constexpr size_t O_WQT = O_VW + SZ_TOK_BF;
  constexpr size_t O_WKT = O_WQT + SZ_W_BF;
  constexpr size_t O_WVT = O_WKT + SZ_W_BF;
  constexpr size_t O_WOT = O_WVT + SZ_W_BF;
  constexpr size_t O_A1T = O_WOT + SZ_W_BF;
  constexpr size_t O_B1T = O_A1T + 65536;
  constexpr size_t O_A2T = O_B1T + 262144;
  constexpr size_t O_B2T = O_A2T + 262144;
  constexpr size_t O_AO = O_B2T + 65536;
  constexpr size_t O_SRCB = O_AO + SZ_TOK_BF;

  u16* Qw_ = (u16*)(ws + O_QW);
  u16* Kw_ = (u16*)(ws + O_KW);
  u16* Vw_ = (u16*)(ws + O_VW);
  u16* WqT = (u16*)(ws + O_WQT);
  u16* WkT = (u16*)(ws + O_WKT);
  u16* WvT = (u16*)(ws + O_WVT);
  u16* WoT = (u16*)(ws + O_WOT);
  u16* A1T = (u16*)(ws + O_A1T);
  u16* B1T = (u16*)(ws + O_B1T);
  u16* A2T = (u16*)(ws + O_A2T);
  u16* B2T = (u16*)(ws + O_B2T);
  u16* ao = (u16*)(ws + O_AO);
  u16* srcb = (u16*)(ws + O_SRCB);

  // 1) weight transposes only
  prep_w<<<336, 256, 0, stream>>>(Wq, Wk, Wv, Wo, A1, B1, A2, B2,
                                  WqT, WkT, WvT, WoT, A1T, B1T, A2T, B2T);

  // 2) QKV projections straight from f32 inputs (Q in exp2 domain)
  qkv_fused<<<dim3(4, 64, 3), 256, 0, stream>>>(q, k, v, WqT, WkT, WvT,
                                                bq, bk, bv, Qw_, Kw_, Vw_);

  // 3) fused attention (r12-proven, unchanged)
  attn_kernel<<<dim3(64, 64), 512, 0, stream>>>(Qw_, Kw_, Vw_, topk, ao);

  // 4) Wo + bias + residual(q) + LN1 -> srcb
  gemm_ln1<<<512, 256, 0, stream>>>(ao, WoT, bo, q, g1, be1, srcb);

  // 5) FFN + B2 + residual(srcb) + LN2 -> d_out, all in one kernel
  ffn3_ln<<<256, 256, 0, stream>>>(srcb, A1T, B1T, A2T, B2T, g2, be2, (float*)d_out);
}

// Round 15
// 250.615 us; speedup vs baseline: 1.0397x; 1.0187x over previous
//
#include <hip/hip_runtime.h>

typedef unsigned short u16;
typedef unsigned int u32;
typedef unsigned long long u64;
using s16x8 = __attribute__((ext_vector_type(8))) short;
using s16x4 = __attribute__((ext_vector_type(4))) short;
using u16x4 = __attribute__((ext_vector_type(4))) unsigned short;
using u32x4 = __attribute__((ext_vector_type(4))) unsigned int;
using f32x4 = __attribute__((ext_vector_type(4))) float;

__device__ __forceinline__ u16 f2bf(float f) {
  unsigned int u = __float_as_uint(f);
  u += 0x7FFFu + ((u >> 16) & 1u);
  return (u16)(u >> 16);
}
__device__ __forceinline__ float bf2f(u16 b) {
  return __uint_as_float(((u32)b) << 16);
}
__device__ __forceinline__ u32 pkbf(float a, float b) {
  u32 r;
  asm("v_cvt_pk_bf16_f32 %0, %1, %2" : "=v"(r) : "v"(a), "v"(b));
  return r;
}
// single v_cmp producing a 64-bit lane mask in SGPRs: key >= cand
__device__ __forceinline__ u64 cmp_ge(u32 key, u32 cand) {
  u64 m;
  asm("v_cmp_le_u32 %0, %1, %2" : "=s"(m) : "s"(cand), "v"(key));
  return m;
}
// monotone 16-bit key from f32 (sign-flip trick, truncated) — r9-proven
__device__ __forceinline__ u32 f2key(float f) {
  u32 u = __float_as_uint(f);
  u32 flip = (u32)((int)u >> 31) | 0x80000000u;
  return (u ^ flip) >> 16;
}
// inverse: 16-bit key -> f32 (truncated value)
__device__ __forceinline__ float key2f(u32 k) {
  u32 t = k << 16;
  u32 msk = ((int)t < 0) ? 0x80000000u : 0xFFFF0000u;
  return __uint_as_float(t ^ msk);
}

// ---------------- prep: weight transposes only (64x64 LDS tiles) ----------------
__global__ __launch_bounds__(256) void prep_w(
    const float* __restrict__ Wq, const float* __restrict__ Wk, const float* __restrict__ Wv,
    const float* __restrict__ Wo, const float* __restrict__ A1, const float* __restrict__ B1,
    const float* __restrict__ A2, const float* __restrict__ B2,
    u16* __restrict__ WqT, u16* __restrict__ WkT, u16* __restrict__ WvT, u16* __restrict__ WoT,
    u16* __restrict__ A1T, u16* __restrict__ B1T, u16* __restrict__ A2T, u16* __restrict__ B2T) {
  __shared__ u16 t[64][68];
  int b = blockIdx.x, tid = threadIdx.x;
  const float* src; u16* dst; int base, R, C;
  if (b < 64)        { src = Wq; dst = WqT; base = 0;   R = 512;  C = 512; }
  else if (b < 128)  { src = Wk; dst = WkT; base = 64;  R = 512;  C = 512; }
  else if (b < 192)  { src = Wv; dst = WvT; base = 128; R = 512;  C = 512; }
  else if (b < 256)  { src = Wo; dst = WoT; base = 192; R = 512;  C = 512; }
  else if (b < 264)  { src = A1; dst = A1T; base = 256; R = 512;  C = 64;  }
  else if (b < 296)  { src = B1; dst = B1T; base = 264; R = 64;   C = 2048;}
  else if (b < 328)  { src = A2; dst = A2T; base = 296; R = 2048; C = 64;  }
  else               { src = B2; dst = B2T; base = 328; R = 64;   C = 512; }
  int ti = b - base;
  int tpr = C >> 6;
  int r0 = (ti / tpr) * 64, c0 = (ti % tpr) * 64;
#pragma unroll
  for (int i = 0; i < 4; ++i) {
    int r = i * 16 + (tid >> 4), c = (tid & 15) * 4;
    float4 f = *(const float4*)&src[(size_t)(r0 + r) * C + c0 + c];
    t[r][c] = f2bf(f.x); t[r][c + 1] = f2bf(f.y);
    t[r][c + 2] = f2bf(f.z); t[r][c + 3] = f2bf(f.w);
  }
  __syncthreads();
#pragma unroll
  for (int i = 0; i < 4; ++i) {
    int cc = i * 16 + (tid >> 4), rr = (tid & 15) * 4;
    u16x4 o;
    o[0] = t[rr][cc]; o[1] = t[rr + 1][cc]; o[2] = t[rr + 2][cc]; o[3] = t[rr + 3][cc];
    *(u16x4*)&dst[(size_t)(c0 + cc) * R + r0 + rr] = o;
  }
}

// ---------------- fused QKV projection from f32 inputs: 128x128 tiles, grid (4,64,3) ----
// z=0: Q (scaled 0.125*log2e, scatter [nh][l][d]); z=1: K ([nh][l][d]); z=2: V ([nh][d][l]).
__global__ __launch_bounds__(256, 4) void qkv_fused(
    const float* __restrict__ q, const float* __restrict__ k, const float* __restrict__ v,
    const u16* __restrict__ WqT, const u16* __restrict__ WkT, const u16* __restrict__ WvT,
    const float* __restrict__ bq, const float* __restrict__ bk, const float* __restrict__ bv,
    u16* __restrict__ Qw, u16* __restrict__ Kw, u16* __restrict__ Vw) {
  __shared__ __align__(16) u16 As[128][72];
  __shared__ __align__(16) u16 Bs[128][72];
  const int z = blockIdx.z;
  const float* A = z == 0 ? q : (z == 1 ? k : v);
  const u16* Bt = z == 0 ? WqT : (z == 1 ? WkT : WvT);
  const float* bias = z == 0 ? bq : (z == 1 ? bk : bv);
  u16* outp = z == 0 ? Qw : (z == 1 ? Kw : Vw);

  const int tid = threadIdx.x;
  const int m0 = blockIdx.y * 128, n0 = blockIdx.x * 128;
  const int lane = tid & 63, wid = tid >> 6;
  const int l16 = lane & 15, hi = lane >> 4;
  const int wr = (wid >> 1) * 64, wc = (wid & 1) * 64;

  f32x4 acc[4][4];
#pragma unroll
  for (int i = 0; i < 4; ++i)
#pragma unroll
    for (int j = 0; j < 4; ++j) acc[i][j] = (f32x4){0.f, 0.f, 0.f, 0.f};

  for (int k0 = 0; k0 < 512; k0 += 64) {
    if (k0) __syncthreads();
#pragma unroll
    for (int i = 0; i < 4; ++i) {
      int idx = i * 256 + tid;
      int r = idx >> 3, cc = (idx & 7) * 8;
      float4 f0 = *(const float4*)&A[(size_t)(m0 + r) * 512 + k0 + cc];
      float4 f1 = *(const float4*)&A[(size_t)(m0 + r) * 512 + k0 + cc + 4];
      u32x4 pk;
      pk[0] = pkbf(f0.x, f0.y); pk[1] = pkbf(f0.z, f0.w);
      pk[2] = pkbf(f1.x, f1.y); pk[3] = pkbf(f1.z, f1.w);
      *(u32x4*)&As[r][cc] = pk;
      *(s16x8*)&Bs[r][cc] = *(const s16x8*)&Bt[(size_t)(n0 + r) * 512 + k0 + cc];
    }
    __syncthreads();
#pragma unroll
    for (int kk = 0; kk < 2; ++kk) {
      const int kb_ = kk * 32 + hi * 8;
      s16x8 af[4], bf[4];
#pragma unroll
      for (int mf = 0; mf < 4; ++mf) af[mf] = *(const s16x8*)&As[wr + mf * 16 + l16][kb_];
#pragma unroll
      for (int nf = 0; nf < 4; ++nf) bf[nf] = *(const s16x8*)&Bs[wc + nf * 16 + l16][kb_];
#pragma unroll
      for (int mf = 0; mf < 4; ++mf)
#pragma unroll
        for (int nf = 0; nf < 4; ++nf)
          acc[mf][nf] = __builtin_amdgcn_mfma_f32_16x16x32_bf16(af[mf], bf[nf], acc[mf][nf], 0, 0, 0);
    }
  }

#pragma unroll
  for (int mf = 0; mf < 4; ++mf)
#pragma unroll
    for (int nf = 0; nf < 4; ++nf)
#pragma unroll
      for (int i = 0; i < 4; ++i) {
        int row = m0 + wr + mf * 16 + hi * 4 + i;
        int col = n0 + wc + nf * 16 + l16;
        float val = acc[mf][nf][i] + bias[col];
        if (z == 0) val *= 0.18033688f;  // (1/sqrt(64)) * log2(e): exp2-domain scores
        int l = row >> 3, n = row & 7, hh = col >> 6, d = col & 63;
        if (z < 2)
          outp[(((size_t)(n * 8 + hh) * 1024 + l) << 6) + d] = f2bf(val);
        else
          outp[((size_t)(n * 8 + hh) * 64 + d) * 1024 + l] = f2bf(val);
      }
}

// ---------------- fused attention: QK^T -> top-k mask -> softmax -> PV ----------------
// grid (L/16, 64), 512 threads (8 waves), QBLK=16 -> ~39.3KB LDS -> 4 blocks/CU.
// Phases A/B r12-proven, UNCHANGED. Phase C now uses ALL 8 waves:
// wave w owns d-block (w&3)*16 and ks-half (w>>2); waves 4-7 deposit partials
// in LDS, one barrier, waves 0-3 combine + scale + store.
__global__ __launch_bounds__(512, 8) void attn_kernel(const u16* __restrict__ Qw,
                                                      const u16* __restrict__ Kw,
                                                      const u16* __restrict__ Vw,
                                                      const float* __restrict__ topk,
                                                      u16* __restrict__ ao) {
  __shared__ __align__(16) u16 scb[16 * 1024];  // 32KB: keys -> P (bf16), XOR-swizzled
  __shared__ __align__(16) u16 Qt[16][72];
  __shared__ float invs[16];
  __shared__ __align__(16) f32x4 partl[4][64];  // Phase-C partials from waves 4-7
  const int tid = threadIdx.x, lane = tid & 63, wid = tid >> 6;
  const int l16 = lane & 15, hi = lane >> 4;
  const int mb = blockIdx.x, nh = blockIdx.y;

  const int kkeep = (int)(1024.f / (1.f + __expf(-topk[0])));

  // stage Q tile (16 x 64)
  if (tid < 256) {
    int r = tid >> 4, dc = (tid & 15) << 2;
    *(s16x4*)&Qt[r][dc] =
        *(const s16x4*)&Qw[((size_t)nh * 1024 + mb * 16 + r) * 64 + dc];
  }
  __syncthreads();

  // ---- Phase A: keys = key(QK^T), K prefetched one nf ahead. Wave w: s in [128w,128w+128).
  {
    const u16* Kb = Kw + (size_t)nh * 1024 * 64;
    s16x8 bq0 = *(const s16x8*)&Qt[l16][hi * 8];
    s16x8 bq1 = *(const s16x8*)&Qt[l16][32 + hi * 8];
    const int s0 = wid * 128;
    const size_t kbase = (size_t)(s0 + l16) * 64 + hi * 8;
    s16x8 c0 = *(const s16x8*)&Kb[kbase];
    s16x8 c1 = *(const s16x8*)&Kb[kbase + 32];
    char* rowq = (char*)scb + l16 * 2048;
    const int Xq = (l16 & 7) << 4;
#pragma unroll
    for (int nf = 0; nf < 8; ++nf) {
      const size_t nb = kbase + (size_t)(nf < 7 ? nf + 1 : nf) * 1024;  // clamped: always valid
      s16x8 n0_ = *(const s16x8*)&Kb[nb];
      s16x8 n1_ = *(const s16x8*)&Kb[nb + 32];
      f32x4 acc = {0.f, 0.f, 0.f, 0.f};
      acc = __builtin_amdgcn_mfma_f32_16x16x32_bf16(c0, bq0, acc, 0, 0, 0);
      acc = __builtin_amdgcn_mfma_f32_16x16x32_bf16(c1, bq1, acc, 0, 0, 0);
      u32 k0 = f2key(acc[0]) | (f2key(acc[1]) << 16);
      u32 k1 = f2key(acc[2]) | (f2key(acc[3]) << 16);
      int boff = (2 * (s0 + nf * 16 + 4 * hi)) ^ Xq;
      *(uint2*)(rowq + boff) = make_uint2(k0, k1);
      c0 = n0_; c1 = n1_;
    }
  }
  __syncthreads();

  // ---- Phase B: wave processes its 2 rows SEQUENTIALLY (1 row = 16 key VGPRs live).
  for (int rp = 0; rp < 2; ++rp) {
    const int r = wid * 2 + rp;
    char* rb = (char*)scb + r * 2048;
    const int X = (r & 7) << 4;
    const int oa = (16 * lane) ^ X, ob = (16 * lane + 1024) ^ X;
    u32x4 qa = *(const u32x4*)(rb + oa), qb_ = *(const u32x4*)(rb + ob);
    u32 ka[16];
#pragma unroll
    for (int j = 0; j < 4; ++j) {
      ka[2 * j] = qa[j] & 0xFFFFu; ka[2 * j + 1] = qa[j] >> 16;
      ka[8 + 2 * j] = qb_[j] & 0xFFFFu; ka[9 + 2 * j] = qb_[j] >> 16;
    }
    u32 T = 0;
    for (int bit = 15; bit >= 0; --bit) {
      u32 c = T + (1u << bit);
      int n = 0;
#pragma unroll
      for (int j = 0; j < 16; ++j) n += __builtin_popcountll(cmp_ge(ka[j], c));
      T = (n >= kkeep) ? c : T;
    }
    const float tv = key2f(T);
    float s = 0.f;
    u32x4 wa, wb;
#pragma unroll
    for (int j = 0; j < 4; ++j) {
      float e0 = (ka[2 * j] >= T) ? __builtin_amdgcn_exp2f(key2f(ka[2 * j]) - tv) : 0.f;
      float e1 = (ka[2 * j + 1] >= T) ? __builtin_amdgcn_exp2f(key2f(ka[2 * j + 1]) - tv) : 0.f;
      float e2 = (ka[8 + 2 * j] >= T) ? __builtin_amdgcn_exp2f(key2f(ka[8 + 2 * j]) - tv) : 0.f;
      float e3 = (ka[9 + 2 * j] >= T) ? __builtin_amdgcn_exp2f(key2f(ka[9 + 2 * j]) - tv) : 0.f;
      s += e0 + e1 + e2 + e3;
      wa[j] = pkbf(e0, e1); wb[j] = pkbf(e2, e3);
    }
    *(u32x4*)(rb + oa) = wa; *(u32x4*)(rb + ob) = wb;
#pragma unroll
    for (int off = 1; off < 64; off <<= 1) s += __shfl_xor(s, off);
    if (lane == 0) invs[r] = __builtin_amdgcn_rcpf(s);
  }
  __syncthreads();

  // ---- Phase C: out = (P @ V) * inv, ALL 8 waves ----
  {
    const u16* Vb = Vw + (size_t)nh * 64 * 1024;
    const int d0 = (wid & 3) * 16;
    const int ks0 = (wid >> 2) * 16;   // ks half: 0..15 or 16..31
    f32x4 oacc0 = {0.f, 0.f, 0.f, 0.f};
    f32x4 oacc1 = {0.f, 0.f, 0.f, 0.f};
    const char* Pbase = (const char*)scb + l16 * 2048;
    const int Xp = (l16 & 7) << 4;
    const size_t vbase = (size_t)(d0 + l16) * 1024 + hi * 8;
    s16x8 v0 = *(const s16x8*)&Vb[vbase + (size_t)ks0 * 32];
    s16x8 v1 = *(const s16x8*)&Vb[vbase + (size_t)(ks0 + 1) * 32];
#pragma unroll
    for (int kt = 0; kt < 16; kt += 2) {
      const int ks = ks0 + kt;
      const int kss = (kt < 14) ? ks + 2 : ks;  // clamped: stays within the V row
      s16x8 nv0 = *(const s16x8*)&Vb[vbase + (size_t)kss * 32];
      s16x8 nv1 = *(const s16x8*)&Vb[vbase + (size_t)(kss + 1) * 32];
      s16x8 a0 = *(const s16x8*)(Pbase + ((ks * 64 + hi * 16) ^ Xp));
      s16x8 a1 = *(const s16x8*)(Pbase + (((ks + 1) * 64 + hi * 16) ^ Xp));
      oacc0 = __builtin_amdgcn_mfma_f32_16x16x32_bf16(a0, v0, oacc0, 0, 0, 0);
      oacc1 = __builtin_amdgcn_mfma_f32_16x16x32_bf16(a1, v1, oacc1, 0, 0, 0);
      v0 = nv0; v1 = nv1;
    }
    f32x4 part;
#pragma unroll
    for (int i = 0; i < 4; ++i) part[i] = oacc0[i] + oacc1[i];
    if (wid >= 4) partl[wid - 4][lane] = part;
    __syncthreads();
    if (wid < 4) {
      f32x4 other = partl[wid][lane];
      const int n = nh >> 3, hh = nh & 7;
#pragma unroll
      for (int i = 0; i < 4; ++i) {
        int l = mb * 16 + hi * 4 + i;
        int d = d0 + l16;
        float vv = (part[i] + other[i]) * invs[hi * 4 + i];
        ao[(size_t)(l * 8 + n) * 512 + d * 8 + hh] = f2bf(vv);
      }
    }
  }
}

// ---------------- GEMM (BM=16, N=512, K=512) + bias + resid(q,f32) + LayerNorm1 -> bf16 ----
__global__ __launch_bounds__(256, 2) void gemm_ln1(const u16* __restrict__ A,
                                                   const u16* __restrict__ Bt,
                                                   const float* __restrict__ bias,
                                                   const float* __restrict__ residf,
                                                   const float* __restrict__ g,
                                                   const float* __restrict__ be,
                                                   u16* __restrict__ outb) {
  constexpr int K = 512;
  __shared__ __align__(16) u16 As[16][72];
  __shared__ float red_s[4][16];
  __shared__ float red_q[4][16];
  const int tid = threadIdx.x;
  const int lane = tid & 63, wid = tid >> 6;
  const int l16 = lane & 15, hi = lane >> 4;
  const int m0 = blockIdx.x * 16;
  const int wc = wid * 128;

  f32x4 acc[8];
#pragma unroll
  for (int nf = 0; nf < 8; ++nf) acc[nf] = (f32x4){0.f, 0.f, 0.f, 0.f};

  for (int k0 = 0; k0 < K; k0 += 64) {
    if (k0) __syncthreads();
    {
      int r = tid >> 4, c = (tid & 15) << 2;
      *(s16x4*)&As[r][c] = *(const s16x4*)&A[(size_t)(m0 + r) * K + k0 + c];
    }
    __syncthreads();
#pragma unroll
    for (int kk = 0; kk < 2; ++kk) {
      const int kb_ = kk * 32 + hi * 8;
      s16x8 a = *(const s16x8*)&As[l16][kb_];
#pragma unroll
      for (int nf = 0; nf < 8; ++nf) {
        s16x8 b = *(const s16x8*)&Bt[(size_t)(wc + nf * 16 + l16) * K + k0 + kb_];
        acc[nf] = __builtin_amdgcn_mfma_f32_16x16x32_bf16(a, b, acc[nf], 0, 0, 0);
      }
    }
  }

#pragma unroll
  for (int nf = 0; nf < 8; ++nf) {
    int col = wc + nf * 16 + l16;
#pragma unroll
    for (int i = 0; i < 4; ++i) {
      int row = m0 + hi * 4 + i;
      acc[nf][i] += bias[col] + residf[(size_t)row * 512 + col];
    }
  }
  float s[4] = {0.f, 0.f, 0.f, 0.f}, q2[4] = {0.f, 0.f, 0.f, 0.f};
#pragma unroll
  for (int nf = 0; nf < 8; ++nf)
#pragma unroll
    for (int i = 0; i < 4; ++i) {
      s[i] += acc[nf][i];
      q2[i] += acc[nf][i] * acc[nf][i];
    }
#pragma unroll
  for (int i = 0; i < 4; ++i) {
#pragma unroll
    for (int off = 1; off < 16; off <<= 1) {
      s[i] += __shfl_xor(s[i], off);
      q2[i] += __shfl_xor(q2[i], off);
    }
  }
  if (l16 == 0) {
#pragma unroll
    for (int i = 0; i < 4; ++i) {
      red_s[wid][hi * 4 + i] = s[i];
      red_q[wid][hi * 4 + i] = q2[i];
    }
  }
  __syncthreads();
  float mean[4], rstd[4];
#pragma unroll
  for (int i = 0; i < 4; ++i) {
    int r = hi * 4 + i;
    float ms = red_s[0][r] + red_s[1][r] + red_s[2][r] + red_s[3][r];
    float mq = red_q[0][r] + red_q[1][r] + red_q[2][r] + red_q[3][r];
    mean[i] = ms * (1.f / 512.f);
    float var = mq * (1.f / 512.f) - mean[i] * mean[i];
    rstd[i] = rsqrtf(var + 1e-5f);
  }
#pragma unroll
  for (int nf = 0; nf < 8; ++nf) {
    int col = wc + nf * 16 + l16;
    float gv = g[col], bev = be[col];
#pragma unroll
    for (int i = 0; i < 4; ++i) {
      int row = m0 + hi * 4 + i;
      float y = (acc[nf][i] - mean[i]) * rstd[i] * gv + bev;
      outb[(size_t)row * 512 + col] = f2bf(y);
    }
  }
}

// ---------------- fused low-rank FFN + B2 + residual + LN2: BM=16, grid 512 ----------------
// stage1: u(16x64) = srcb@A1T. stage2: w2 = sum_jc relu(u@B1c)@A2c.
// stage3: out(16x512) = w2@B2T + srcb; LN2 -> d_out (f32). 2 blocks/CU now.
__global__ __launch_bounds__(256, 2) void ffn3_ln(const u16* __restrict__ srcb,
                                                  const u16* __restrict__ A1T,
                                                  const u16* __restrict__ B1T,
                                                  const u16* __restrict__ A2T,
                                                  const u16* __restrict__ B2T,
                                                  const float* __restrict__ g,
                                                  const float* __restrict__ be,
                                                  float* __restrict__ outf) {
  __shared__ __align__(16) u16 As[16][72];   // srcb staging; later the w2 tile
  __shared__ __align__(16) u16 Bs[64][72];
  __shared__ __align__(16) u16 Us[16][72];
  __shared__ __align__(16) u16 B1s[64][72];
  __shared__ __align__(16) u16 A2s[64][72];
  __shared__ __align__(16) u16 Hs[16][72];
  __shared__ float red_s[4][16];
  __shared__ float red_q[4][16];
  const int tid = threadIdx.x;
  const int lane = tid & 63, wid = tid >> 6;
  const int l16 = lane & 15, hi = lane >> 4;
  const int m0 = blockIdx.x * 16;
  const int wn = wid * 16;

  // ---- stage 1: u(16x64) = srcb_tile @ A1T^T ----
  f32x4 accu = (f32x4){0.f, 0.f, 0.f, 0.f};
  for (int k0 = 0; k0 < 512; k0 += 64) {
    if (k0) __syncthreads();
    {
      int r = tid >> 4, c = (tid & 15) << 2;
      *(s16x4*)&As[r][c] = *(const s16x4*)&srcb[(size_t)(m0 + r) * 512 + k0 + c];
    }
#pragma unroll
    for (int i = 0; i < 2; ++i) {
      int idx = i * 256 + tid;
      int r = idx >> 3, c = (idx & 7) << 3;
      *(s16x8*)&Bs[r][c] = *(const s16x8*)&A1T[(size_t)r * 512 + k0 + c];
    }
    __syncthreads();
#pragma unroll
    for (int kk = 0; kk < 2; ++kk) {
      const int kb_ = kk * 32 + hi * 8;
      s16x8 a = *(const s16x8*)&As[l16][kb_];
      s16x8 b = *(const s16x8*)&Bs[wn + l16][kb_];
      accu = __builtin_amdgcn_mfma_f32_16x16x32_bf16(a, b, accu, 0, 0, 0);
    }
  }
  __syncthreads();
#pragma unroll
  for (int i = 0; i < 4; ++i)
    Us[hi * 4 + i][wn + l16] = f2bf(accu[i]);

  // ---- stage 2: w2(16x64) = sum over 32 jc chunks of relu(u@B1c)@A2c ----
  f32x4 w2a = (f32x4){0.f, 0.f, 0.f, 0.f};
  for (int jc = 0; jc < 32; ++jc) {
#pragma unroll
    for (int i = 0; i < 2; ++i) {
      int idx = i * 256 + tid;
      int r = idx >> 3, c = (idx & 7) << 3;
      *(s16x8*)&B1s[r][c] = *(const s16x8*)&B1T[(size_t)(jc * 64 + r) * 64 + c];
      *(s16x8*)&A2s[r][c] = *(const s16x8*)&A2T[(size_t)r * 2048 + jc * 64 + c];
    }
    __syncthreads();
    f32x4 ha = (f32x4){0.f, 0.f, 0.f, 0.f};
#pragma unroll
    for (int kk = 0; kk < 2; ++kk) {
      const int kb_ = kk * 32 + hi * 8;
      s16x8 a = *(const s16x8*)&Us[l16][kb_];
      s16x8 b = *(const s16x8*)&B1s[wn + l16][kb_];
      ha = __builtin_amdgcn_mfma_f32_16x16x32_bf16(a, b, ha, 0, 0, 0);
    }
#pragma unroll
    for (int i = 0; i < 4; ++i)
      Hs[hi * 4 + i][wn + l16] = f2bf(fmaxf(ha[i], 0.f));
    __syncthreads();
#pragma unroll
    for (int kk = 0; kk < 2; ++kk) {
      const int kb_ = kk * 32 + hi * 8;
      s16x8 a = *(const s16x8*)&Hs[l16][kb_];
      s16x8 b = *(const s16x8*)&A2s[wn + l16][kb_];
      w2a = __builtin_amdgcn_mfma_f32_16x16x32_bf16(a, b, w2a, 0, 0, 0);
    }
    __syncthreads();
  }

  // ---- stage 3: w2 tile -> LDS (reuse As); out = w2@B2T + srcb; LN2 -> d_out ----
#pragma unroll
  for (int i = 0; i < 4; ++i)
    As[hi * 4 + i][wn + l16] = f2bf(w2a[i]);
  __syncthreads();

  const int wc = wid * 128;
  f32x4 acc[8];
#pragma unroll
  for (int nf = 0; nf < 8; ++nf) acc[nf] = (f32x4){0.f, 0.f, 0.f, 0.f};
#pragma unroll
  for (int kk = 0; kk < 2; ++kk) {
    const int kb_ = kk * 32 + hi * 8;
    s16x8 a = *(const s16x8*)&As[l16][kb_];
#pragma unroll
    for (int nf = 0; nf < 8; ++nf) {
      s16x8 b = *(const s16x8*)&B2T[(size_t)(wc + nf * 16 + l16) * 64 + kb_];
      acc[nf] = __builtin_amdgcn_mfma_f32_16x16x32_bf16(a, b, acc[nf], 0, 0, 0);
    }
  }
  float s_[4] = {0.f, 0.f, 0.f, 0.f}, q2_[4] = {0.f, 0.f, 0.f, 0.f};
#pragma unroll
  for (int nf = 0; nf < 8; ++nf) {
    int col = wc + nf * 16 + l16;
#pragma unroll
    for (int i = 0; i < 4; ++i) {
      int row = m0 + hi * 4 + i;
      float v = acc[nf][i] + bf2f(srcb[(size_t)row * 512 + col]);
      acc[nf][i] = v;
      s_[i] += v;
      q2_[i] += v * v;
    }
  }
#pragma unroll
  for (int i = 0; i < 4; ++i) {
#pragma unroll
    for (int off = 1; off < 16; off <<= 1) {
      s_[i] += __shfl_xor(s_[i], off);
      q2_[i] += __shfl_xor(q2_[i], off);
    }
  }
  if (l16 == 0) {
#pragma unroll
    for (int i = 0; i < 4; ++i) {
      red_s[wid][hi * 4 + i] = s_[i];
      red_q[wid][hi * 4 + i] = q2_[i];
    }
  }
  __syncthreads();
  float mean[4], rstd[4];
#pragma unroll
  for (int i = 0; i < 4; ++i) {
    int r = hi * 4 + i;
    float ms = red_s[0][r] + red_s[1][r] + red_s[2][r] + red_s[3][r];
    float mq = red_q[0][r] + red_q[1][r] + red_q[2][r] + red_q[3][r];
    mean[i] = ms * (1.f / 512.f);
    float var = mq * (1.f / 512.f) - mean[i] * mean[i];
    rstd[i] = rsqrtf(var + 1e-5f);
  }
#pragma unroll
  for (int nf = 0; nf < 8; ++nf) {
    int col = wc + nf * 16 + l16;
    float gv = g[col], bev = be[col];
#pragma unroll
    for (int i = 0; i < 4; ++i) {
      int row = m0 + hi * 4 + i;
      float y = (acc[nf][i] - mean[i]) * rstd[i] * gv + bev;
      outf[(size_t)row * 512 + col] = y;
    }
  }
}

// ---------------- host launch ----------------
extern "C" void kernel_launch(void* const* d_in, const int* in_sizes, int n_in,
                              void* d_out, int out_size, void* d_ws, size_t ws_size,
                              hipStream_t stream) {
  const float* q = (const float*)d_in[0];
  const float* k = (const float*)d_in[1];
  const float* v = (const float*)d_in[2];
  const float* Wq = (const float*)d_in[3];
  const float* bq = (const float*)d_in[4];
  const float* Wk = (const float*)d_in[5];
  const float* bk = (const float*)d_in[6];
  const float* Wv = (const float*)d_in[7];
  const float* bv = (const float*)d_in[8];
  const float* Wo = (const float*)d_in[9];
  const float* bo = (const float*)d_in[10];
  const float* topk = (const float*)d_in[11];
  const float* A1 = (const float*)d_in[12];
  const float* B1 = (const float*)d_in[13];
  const float* A2 = (const float*)d_in[14];
  const float* B2 = (const float*)d_in[15];
  const float* g1 = (const float*)d_in[16];
  const float* be1 = (const float*)d_in[17];
  const float* g2 = (const float*)d_in[18];
  const float* be2 = (const float*)d_in[19];

  char* ws = (char*)d_ws;
  constexpr size_t SZ_TOK_BF = (size_t)8192 * 512 * 2;
  constexpr size_t SZ_W_BF = (size_t)512 * 512 * 2;
  constexpr size_t O_QW = 0;
  constexpr size_t O_KW = O_QW + SZ_TOK_BF;
  constexpr size_t O_VW = O_KW + SZ_TOK_BF;
  constexpr size_t O_WQT = O_VW + SZ_TOK_BF;
  constexpr size_t O_WKT = O_WQT + SZ_W_BF;
  constexpr size_t O_WVT = O_WKT + SZ_W_BF;
  constexpr size_t O_WOT = O_WVT + SZ_W_BF;
  constexpr size_t O_A1T = O_WOT + SZ_W_BF;
  constexpr size_t O_B1T = O_A1T + 65536;
  constexpr size_t O_A2T = O_B1T + 262144;
  constexpr size_t O_B2T = O_A2T + 262144;
  constexpr size_t O_AO = O_B2T + 65536;
  constexpr size_t O_SRCB = O_AO + SZ_TOK_BF;

  u16* Qw_ = (u16*)(ws + O_QW);
  u16* Kw_ = (u16*)(ws + O_KW);
  u16* Vw_ = (u16*)(ws + O_VW);
  u16* WqT = (u16*)(ws + O_WQT);
  u16* WkT = (u16*)(ws + O_WKT);
  u16* WvT = (u16*)(ws + O_WVT);
  u16* WoT = (u16*)(ws + O_WOT);
  u16* A1T = (u16*)(ws + O_A1T);
  u16* B1T = (u16*)(ws + O_B1T);
  u16* A2T = (u16*)(ws + O_A2T);
  u16* B2T = (u16*)(ws + O_B2T);
  u16* ao = (u16*)(ws + O_AO);
  u16* srcb = (u16*)(ws + O_SRCB);

  // 1) weight transposes only
  prep_w<<<336, 256, 0, stream>>>(Wq, Wk, Wv, Wo, A1, B1, A2, B2,
                                  WqT, WkT, WvT, WoT, A1T, B1T, A2T, B2T);

  // 2) QKV projections straight from f32 inputs (Q in exp2 domain)
  qkv_fused<<<dim3(4, 64, 3), 256, 0, stream>>>(q, k, v, WqT, WkT, WvT,
                                                bq, bk, bv, Qw_, Kw_, Vw_);

  // 3) fused attention (Phases A/B unchanged; Phase C 8-wave ks-split)
  attn_kernel<<<dim3(64, 64), 512, 0, stream>>>(Qw_, Kw_, Vw_, topk, ao);

  // 4) Wo + bias + residual(q) + LN1 -> srcb
  gemm_ln1<<<512, 256, 0, stream>>>(ao, WoT, bo, q, g1, be1, srcb);

  // 5) FFN + B2 + residual(srcb) + LN2 -> d_out (BM=16, 512 blocks, 2/CU)
  ffn3_ln<<<512, 256, 0, stream>>>(srcb, A1T, B1T, A2T, B2T, g2, be2, (float*)d_out);
}